// Round 12
// baseline (436.607 us; speedup 1.0000x reference)
//
#include <hip/hip_runtime.h>

#define I_F 8192
#define O_F 8192
#define NSPLIT 128
#define CHUNK 64               // rows per split (I_F / NSPLIT)
#define NCT 4                  // column tiles
#define CT_COLS 2048           // cols per tile (O_F / NCT)
#define UPR 256                // packed uints per row per tile (CT_COLS/8)
#define QB 8                   // packed loads in flight per thread

// 3-level cndmask tree: select lut[q] from 8 values held in 2 float4 regs.
__device__ __forceinline__ float lut_sel(const float4& lo, const float4& hi, int q) {
    const bool b2 = (q & 4) != 0;
    const float s0 = b2 ? hi.x : lo.x;
    const float s1 = b2 ? hi.y : lo.y;
    const float s2 = b2 ? hi.z : lo.z;
    const float s3 = b2 ? hi.w : lo.w;
    const bool b1 = (q & 2) != 0;
    const float t0 = b1 ? s2 : s0;
    const float t1 = b1 ? s3 : s1;
    return (q & 1) ? t1 : t0;
}

// Build xT[i][b] = x[b][i] (32B contiguous per i). grid = 32 x 256.
__global__ __launch_bounds__(256) void prolog_kernel(const float* __restrict__ x,
                                                     float* __restrict__ xT) {
    const int t = blockIdx.x * 256 + threadIdx.x;   // 0..8191
    float4 lo, hi;
    lo.x = x[0 * I_F + t];
    lo.y = x[1 * I_F + t];
    lo.z = x[2 * I_F + t];
    lo.w = x[3 * I_F + t];
    hi.x = x[4 * I_F + t];
    hi.y = x[5 * I_F + t];
    hi.z = x[6 * I_F + t];
    hi.w = x[7 * I_F + t];
    ((float4*)xT)[t * 2]     = lo;
    ((float4*)xT)[t * 2 + 1] = hi;
}

// Pack qidx (int32, values 0-7) to 4 bits each, reading LINEARLY (the access
// shape measured at 6.6 TB/s in R11's probe) and writing a block-linear
// layout pk[ct][split][r][cg] so each dense block's slab is contiguous.
// grid = 4096 x 256, 8 grid-stride iters; per iter a wave reads 2 KB linear.
__global__ __launch_bounds__(256) void pack_kernel(const int* __restrict__ qidx,
                                                   unsigned* __restrict__ pk) {
    const size_t nthr = (size_t)gridDim.x * 256;
    const size_t total = (size_t)I_F * O_F / 8;    // 8M output uints
    for (size_t u = (size_t)blockIdx.x * 256 + threadIdx.x; u < total; u += nthr) {
        const int4 a = ((const int4*)qidx)[u * 2];
        const int4 b = ((const int4*)qidx)[u * 2 + 1];
        const unsigned v = (unsigned)(a.x & 7)        | ((unsigned)(a.y & 7) << 4)  |
                           ((unsigned)(a.z & 7) << 8) | ((unsigned)(a.w & 7) << 12) |
                           ((unsigned)(b.x & 7) << 16)| ((unsigned)(b.y & 7) << 20) |
                           ((unsigned)(b.z & 7) << 24)| ((unsigned)(b.w & 7) << 28);
        const int row    = (int)(u >> 10);          // u / 1024 (uints per row)
        const int colgrp = (int)(u & 1023);
        const int ct     = colgrp >> 8;             // / UPR
        const int cg     = colgrp & 255;
        const int split  = row >> 6;                // / CHUNK
        const int r      = row & 63;
        pk[(((size_t)ct * NSPLIT + split) * CHUNK + r) * UPR + cg] = v;
    }
}

// Dense partial from packed indices. Thread owns 8 consecutive cols; per
// row-step it reads ONE uint. Block (ct,split) sweeps a fully CONTIGUOUS
// 64 KB slab of pk (L3-resident, 32 MB total). grid = (NCT, NSPLIT).
// VALU-bound by design (~136 VALU/uint); launch_bounds(256,2) avoids spill
// (est ~156 live VGPR).
__global__ __launch_bounds__(256, 2) void dense_kernel(const unsigned* __restrict__ pk,
                                                       const float* __restrict__ lut,
                                                       const float* __restrict__ xT,
                                                       float* __restrict__ P) {
    __shared__ float4 xs[CHUNK][2];    // xs[r] = {x[0..3][i0+r], x[4..7][i0+r]}

    const int tid = threadIdx.x;
    const int ct = blockIdx.x;
    const int split = blockIdx.y;
    const int col0 = ct * CT_COLS + tid * 8;
    const int i0 = split * CHUNK;

    if (tid < CHUNK * 2)
        ((float4*)xs)[tid] = ((const float4*)(xT + (size_t)i0 * 8))[tid];

    // 8 columns' LUT rows: 8 f32 each -> 2 float4 regs/col (64 VGPR).
    float4 lA[8], lB[8];
#pragma unroll
    for (int c = 0; c < 8; ++c) {
        const float4* p = (const float4*)(lut + (size_t)(col0 + c) * 8);
        lA[c] = p[0];
        lB[c] = p[1];
    }

    float acc[8][8];
#pragma unroll
    for (int c = 0; c < 8; ++c)
#pragma unroll
        for (int b = 0; b < 8; ++b) acc[c][b] = 0.0f;

    __syncthreads();

    const unsigned* slab = pk + ((size_t)ct * NSPLIT + split) * (CHUNK * UPR);

    for (int t = 0; t < CHUNK; t += QB) {
        unsigned qb[QB];
#pragma unroll
        for (int k = 0; k < QB; ++k)
            qb[k] = slab[(t + k) * UPR + tid];

#pragma unroll
        for (int k = 0; k < QB; ++k) {
            const unsigned v  = qb[k];
            const float4 xlo = xs[t + k][0];
            const float4 xhi = xs[t + k][1];
#pragma unroll
            for (int c = 0; c < 8; ++c) {
                const int q = (int)((v >> (4 * c)) & 7u);
                const float w = lut_sel(lA[c], lB[c], q);
                acc[c][0] += xlo.x * w;
                acc[c][1] += xlo.y * w;
                acc[c][2] += xlo.z * w;
                acc[c][3] += xlo.w * w;
                acc[c][4] += xhi.x * w;
                acc[c][5] += xhi.y * w;
                acc[c][6] += xhi.z * w;
                acc[c][7] += xhi.w * w;
            }
        }
    }

    // P layout: [split][b][O_F]; per b two float4 covering the 8 owned cols.
    float* Pb = P + ((size_t)split * 8) * O_F + col0;
#pragma unroll
    for (int b = 0; b < 8; ++b) {
        *(float4*)(Pb + (size_t)b * O_F)     = make_float4(acc[0][b], acc[1][b], acc[2][b], acc[3][b]);
        *(float4*)(Pb + (size_t)b * O_F + 4) = make_float4(acc[4][b], acc[5][b], acc[6][b], acc[7][b]);
    }
}

// Sparse: one wave per output row o; 128 nnz -> 2 per lane; gather from
// L2-resident xT; butterfly-reduce; lane 0 stores 8 values to sp. NO atomics.
__global__ __launch_bounds__(256) void sparse_kernel(const int* __restrict__ rows,
                                                     const int* __restrict__ cols,
                                                     const float* __restrict__ vals,
                                                     const float* __restrict__ xT,
                                                     float* __restrict__ sp) {
    const int wave = threadIdx.x >> 6;
    const int lane = threadIdx.x & 63;
    const int o = blockIdx.x * 4 + wave;
    const int r0 = rows[o];
    const int r1 = rows[o + 1];

    float acc[8];
#pragma unroll
    for (int b = 0; b < 8; ++b) acc[b] = 0.0f;

    for (int k = r0 + lane; k < r1; k += 64) {
        const int   col = cols[k];
        const float v   = vals[k];
        const float4* xp = (const float4*)(xT + (size_t)col * 8);
        const float4 xlo = xp[0];
        const float4 xhi = xp[1];
        acc[0] += v * xlo.x;
        acc[1] += v * xlo.y;
        acc[2] += v * xlo.z;
        acc[3] += v * xlo.w;
        acc[4] += v * xhi.x;
        acc[5] += v * xhi.y;
        acc[6] += v * xhi.z;
        acc[7] += v * xhi.w;
    }

#pragma unroll
    for (int s = 1; s < 64; s <<= 1)
#pragma unroll
        for (int b = 0; b < 8; ++b) acc[b] += __shfl_xor(acc[b], s, 64);

    if (lane == 0) {
#pragma unroll
        for (int b = 0; b < 8; ++b) sp[(size_t)b * O_F + o] = acc[b];
    }
}

// out[t] = sp[t] + sum_s P[s][t]  (t over 8*O_F elems, float4-vectorized).
// grid = 256 x 64.
__global__ __launch_bounds__(64) void reduce_kernel(const float* __restrict__ P,
                                                    const float* __restrict__ sp,
                                                    float* __restrict__ out) {
    const int t4 = blockIdx.x * 64 + threadIdx.x;   // 0..16383 (float4 units)
    float4 s = ((const float4*)sp)[t4];
#pragma unroll 8
    for (int k = 0; k < NSPLIT; ++k) {
        const float4 p = ((const float4*)P)[(size_t)k * (8 * O_F / 4) + t4];
        s.x += p.x; s.y += p.y; s.z += p.z; s.w += p.w;
    }
    ((float4*)out)[t4] = s;
}

extern "C" void kernel_launch(void* const* d_in, const int* in_sizes, int n_in,
                              void* d_out, int out_size, void* d_ws, size_t ws_size,
                              hipStream_t stream) {
    const float* x    = (const float*)d_in[0];
    const int*   qidx = (const int*)d_in[1];
    const float* lut  = (const float*)d_in[2];
    const int*   rows = (const int*)d_in[3];
    const int*   cols = (const int*)d_in[4];
    const float* vals = (const float*)d_in[5];
    float* out = (float*)d_out;

    // Workspace: xT (256KB) | sp (256KB) | P (32MB) | pk (32MB)
    float* xT = (float*)d_ws;
    float* sp = xT + (size_t)I_F * 8;
    float* P  = sp + (size_t)O_F * 8;
    unsigned* pk = (unsigned*)(P + (size_t)NSPLIT * 8 * O_F);

    prolog_kernel<<<I_F / 256, 256, 0, stream>>>(x, xT);
    pack_kernel<<<4096, 256, 0, stream>>>(qidx, pk);
    dense_kernel<<<dim3(NCT, NSPLIT), 256, 0, stream>>>(pk, lut, xT, P);
    sparse_kernel<<<O_F / 4, 256, 0, stream>>>(rows, cols, vals, xT, sp);
    reduce_kernel<<<(8 * O_F / 4) / 64, 64, 0, stream>>>(P, sp, out);
}